// Round 14
// baseline (394.632 us; speedup 1.0000x reference)
//
#include <hip/hip_runtime.h>

// ELKUNet forward on MI355X — round 14. f32 device tensors (proven r1/r2/r4/r5).
// r13 lesson: dual-weight-set preB (128 floats) broke residency AGAIN
// (VGPR=76 < needed; FETCH=1x feats = L1 reloads; 132us). Single 64-float set
// via 16 named float4 is the only proven-resident recipe (r12).
// This round: k_pre1 (r12 verbatim) + self-conv folded into k_segfinal's
// existing conv loop (keep the self bit in the ballot -> k=13 path; conv_w[13]
// L1-hot). pre2 kernel + selfconv buffer (102MB traffic) eliminated.
// Pipeline: memset -> k_scatter -> k_pre1 -> k_segfinal.

typedef unsigned int u32;
typedef unsigned long long u64;

#define EPSV 1e-6f
#define HBITS 19
#define HSIZE (1u << HBITS)
#define HMASK (HSIZE - 1u)

template<int C,int R> __device__ __forceinline__ float dpp_add(float x){
    int y = __builtin_amdgcn_update_dpp(0, __float_as_int(x), C, R, 0xf, true);
    return x + __int_as_float(y);
}
// full 64-lane sum broadcast to all lanes; pure VALU + 1 readlane.
__device__ __forceinline__ float wave_sum(float x){
    x = dpp_add<0xB1,0xF>(x);   // xor 1
    x = dpp_add<0x4E,0xF>(x);   // xor 2
    x = dpp_add<0x141,0xF>(x);  // xor 4
    x = dpp_add<0x140,0xF>(x);  // xor 8
    x = dpp_add<0x142,0xA>(x);  // row_bcast:15
    x = dpp_add<0x143,0xC>(x);  // row_bcast:31
    return __int_as_float(__builtin_amdgcn_readlane(__float_as_int(x), 63));
}

__device__ __forceinline__ u32 hslot(u32 b){ return (b * 0x9E3779B1u) >> (32 - HBITS); }

__global__ void k_scatter(const int* __restrict__ coords, u64* __restrict__ hash,
                          u32* __restrict__ bm, int n){
    int i = blockIdx.x * blockDim.x + threadIdx.x;
    if(i < n){
        int4 c = ((const int4*)coords)[i];
        u32 b = ((u32)c.x << 16) | ((u32)c.y << 8) | (u32)c.z;
        atomicOr(&bm[b >> 5], 1u << (b & 31));
        u64 entry = ((u64)b << 32) | (u32)i;
        u32 s = hslot(b);
        while(atomicCAS(&hash[s], ~0ull, entry) != ~0ull) s = (s + 1) & HMASK;
    }
}

#define MV(f, wq) { a0 = fmaf((f).x, (wq).x, a0); a1 = fmaf((f).y, (wq).y, a1); \
                    a2 = fmaf((f).z, (wq).z, a2); a3 = fmaf((f).w, (wq).w, a3); }

// F_input = LN(feats @ W_pre^T). Weights in 16 NAMED float4 registers (r12).
__launch_bounds__(256, 2)
__global__ void k_pre1(const float* __restrict__ feats, const float* __restrict__ W_pre,
                       const float* __restrict__ lnw, const float* __restrict__ lnb,
                       float* __restrict__ F_input, int n, int nwaves){
    const int lane = threadIdx.x & 63;
    const int wave = (blockIdx.x * blockDim.x + threadIdx.x) >> 6;

    const float4* wr = (const float4*)(W_pre + (size_t)lane * 64);
    float4 w0 = wr[0],  w1 = wr[1],  w2 = wr[2],  w3 = wr[3];
    float4 w4 = wr[4],  w5 = wr[5],  w6 = wr[6],  w7 = wr[7];
    float4 w8 = wr[8],  w9 = wr[9],  wA = wr[10], wB = wr[11];
    float4 wC = wr[12], wD = wr[13], wE = wr[14], wF = wr[15];
    const float lw = lnw[lane], lb = lnb[lane];

    for(int i = wave; i < n; i += nwaves){
        const int si = __builtin_amdgcn_readfirstlane(i);
        const float4* fr = (const float4*)(feats + (size_t)si * 64);
        float a0=0.f, a1=0.f, a2=0.f, a3=0.f;
        MV(fr[0],  w0)  MV(fr[1],  w1)  MV(fr[2],  w2)  MV(fr[3],  w3)
        MV(fr[4],  w4)  MV(fr[5],  w5)  MV(fr[6],  w6)  MV(fr[7],  w7)
        MV(fr[8],  w8)  MV(fr[9],  w9)  MV(fr[10], wA)  MV(fr[11], wB)
        MV(fr[12], wC)  MV(fr[13], wD)  MV(fr[14], wE)  MV(fr[15], wF)
        float acc = (a0 + a1) + (a2 + a3);
        float m = wave_sum(acc) * (1.f/64.f);
        float t = acc - m;
        float v = wave_sum(t*t) * (1.f/64.f);
        F_input[(size_t)si*64 + lane] = t * rsqrtf(v + EPSV) * lw + lb;
    }
}

// 1 wave = 1 segment. Pass1: enumerate own points (bitmap+hash), segment sums
// in registers. Pass2: per point: newF combine + 9-lane neighbor probe + conv
// (SELF INCLUDED via k=13 path) + 2 LNs + relu + out.
__launch_bounds__(256)
__global__ void k_segfinal(const float* __restrict__ F_input,
                           const float* __restrict__ feats,
                           const float* __restrict__ W_pos, const float* __restrict__ alpha,
                           const float* __restrict__ conv_w,
                           const float* __restrict__ ln_w, const float* __restrict__ ln_b,
                           const float* __restrict__ lnl_w, const float* __restrict__ lnl_b,
                           const u64* __restrict__ hash, const u32* __restrict__ bm,
                           float* __restrict__ out){
    const u64* bm64 = (const u64*)bm;
    const int lane = threadIdx.x & 63;
    const int seg  = (blockIdx.x << 2) + (threadIdx.x >> 6);
    const int cx = seg >> 10, cy = (seg >> 5) & 31, cz = seg & 31;

    const int px = (cx << 3) + (lane >> 3), py = (cy << 3) + (lane & 7);
    u64 w = bm64[((size_t)px << 10) | ((u32)py << 2) | (u32)(cz >> 3)];
    u32 o8 = (u32)(w >> ((cz & 7) * 8)) & 0xffu;
    if(__ballot(o8 != 0u) == 0ull) return;

    const float wx = W_pos[lane*3+0], wy = W_pos[lane*3+1], wz = W_pos[lane*3+2];
    const float al = alpha[lane];

    // ---- pass 1: segment sums in registers ----
    float aC = 0.f, aS = 0.f, aL = 0.f;
    u32 t8 = o8;
    while(__ballot(t8 != 0u)){
        int myz = 0, pid = -1;
        if(t8){
            int dz = __ffs(t8) - 1; t8 &= t8 - 1;
            myz = (cz << 3) + dz;
            u32 b = ((u32)px << 16) | ((u32)py << 8) | (u32)myz;
            u32 s = hslot(b); u64 e;
            while((u32)((e = hash[s]) >> 32) != b) s = (s + 1) & HMASK;
            pid = (int)(u32)e;
        }
        u64 mm = __ballot(pid >= 0);
        while(mm){
            int l = __ffsll(mm) - 1; mm &= mm - 1;
            int p  = __builtin_amdgcn_readlane(pid, l);
            int pz = __builtin_amdgcn_readlane(myz, l);
            int qx = (cx << 3) + (l >> 3), qy = (cy << 3) + (l & 7);
            float F = F_input[(size_t)p * 64 + lane];
            float pos = ((float)qx*wx + (float)qy*wy + (float)pz*wz) * al;
            aC = fmaf(F, __cosf(pos), aC);
            aS = fmaf(F, __sinf(pos), aS);
            aL = fmaf(F, pos, aL);
        }
    }
    const float inv = 1.f / wave_sum((float)__popc(o8));
    const float vCv = aC * inv, vSv = aS * inv, vLv = aL * inv;
    const float lnwv = ln_w[lane], lnbv = ln_b[lane];
    const float llwv = lnl_w[lane], llbv = lnl_b[lane];

    // ---- pass 2: per point finale (hash/F re-probes are L1-hot) ----
    t8 = o8;
    while(__ballot(t8 != 0u)){
        int myz = 0, pid = -1;
        if(t8){
            int dz = __ffs(t8) - 1; t8 &= t8 - 1;
            myz = (cz << 3) + dz;
            u32 b = ((u32)px << 16) | ((u32)py << 8) | (u32)myz;
            u32 s = hslot(b); u64 e;
            while((u32)((e = hash[s]) >> 32) != b) s = (s + 1) & HMASK;
            pid = (int)(u32)e;
        }
        u64 mm = __ballot(pid >= 0);
        while(mm){
            int l = __ffsll(mm) - 1; mm &= mm - 1;
            int p  = __builtin_amdgcn_readlane(pid, l);
            int pz = __builtin_amdgcn_readlane(myz, l);
            int qx = (cx << 3) + (l >> 3), qy = (cy << 3) + (l & 7);

            float F = F_input[(size_t)p * 64 + lane];     // L1-hot

            // neighbor probe: lanes 0..8 cover (dx,dy); 3 z-bits each.
            // SELF KEPT (l2=4, t=1 -> k=13): self-conv runs through this loop.
            u32 m3 = 0;
            if(lane < 9){
                int nx = qx + lane/3 - 1, ny = qy + lane%3 - 1;
                if(((u32)nx < 256u) && ((u32)ny < 256u)){
                    const u64* wp = bm64 + (((size_t)nx << 10) | ((u32)ny << 2));
                    int zb = pz & 63;
                    if(zb >= 1 && zb <= 62){
                        u64 ww = wp[pz >> 6];
                        m3 = (u32)((ww >> (zb - 1)) & 7ull);
                    } else {
#pragma unroll
                        for(int t = 0; t < 3; ++t){
                            int zz = pz + t - 1;
                            if((u32)zz < 256u){
                                u64 ww = wp[zz >> 6];
                                m3 |= (u32)((ww >> (zz & 63)) & 1ull) << t;
                            }
                        }
                    }
                }
            }
            u64 b0 = __ballot(m3 & 1u);
            u64 b1 = __ballot(m3 & 2u);
            u64 b2 = __ballot(m3 & 4u);

            float pos = ((float)qx*wx + (float)qy*wy + (float)pz*wz) * al;
            float sn = __sinf(pos), cs = __cosf(pos);
            float newF = fmaf(vCv, cs, fmaf(vSv, sn, vLv - F*pos));
            float local = 0.f;

#pragma unroll
            for(int t = 0; t < 3; ++t){
                u64 mm2 = (t == 0) ? b0 : ((t == 1) ? b1 : b2);
                while(mm2){
                    int l2 = __ffsll(mm2) - 1; mm2 &= mm2 - 1;
                    int nx = qx + l2/3 - 1, ny = qy + l2%3 - 1, nz = pz + t - 1;
                    int k = 3*l2 + t;
                    u32 nb = ((u32)nx << 16) | ((u32)ny << 8) | (u32)nz;
                    u32 s = hslot(nb); u64 e;
                    while((u32)((e = hash[s]) >> 32) != nb) s = (s + 1) & HMASK;
                    const int pin = (int)(u32)e;
                    const float4* gv = (const float4*)(feats + (size_t)pin * 64);
                    const float* cw = conv_w + (size_t)k * 4096;
#pragma unroll 4
                    for(int q = 0; q < 16; ++q){
                        float4 g = gv[q];
                        local = fmaf(g.x, cw[(4*q    )*64 + lane], local);
                        local = fmaf(g.y, cw[(4*q + 1)*64 + lane], local);
                        local = fmaf(g.z, cw[(4*q + 2)*64 + lane], local);
                        local = fmaf(g.w, cw[(4*q + 3)*64 + lane], local);
                    }
                }
            }

            float m1 = wave_sum(newF) * (1.f/64.f);
            float t1 = newF - m1;
            float v1 = wave_sum(t1*t1) * (1.f/64.f);
            float a1 = t1 * rsqrtf(v1 + EPSV) * lnwv + lnbv;

            float m2 = wave_sum(local) * (1.f/64.f);
            float t2 = local - m2;
            float v2 = wave_sum(t2*t2) * (1.f/64.f);
            float a2 = t2 * rsqrtf(v2 + EPSV) * llwv + llbv;

            out[(size_t)p*64 + lane] = fmaxf(a1 + a2, 0.f);
        }
    }
}

extern "C" void kernel_launch(void* const* d_in, const int* in_sizes, int n_in,
                              void* d_out, int out_size, void* d_ws, size_t ws_size,
                              hipStream_t stream) {
    (void)n_in; (void)out_size; (void)ws_size;
    const float* feats    = (const float*)d_in[0];
    const float* W_pre    = (const float*)d_in[1];
    const float* ln_pre_w = (const float*)d_in[2];
    const float* ln_pre_b = (const float*)d_in[3];
    const float* W_pos    = (const float*)d_in[4];
    const float* alpha    = (const float*)d_in[5];
    const float* conv_w   = (const float*)d_in[6];
    const float* ln_w     = (const float*)d_in[7];
    const float* ln_b     = (const float*)d_in[8];
    const float* lnl_w    = (const float*)d_in[9];
    const float* lnl_b    = (const float*)d_in[10];
    const int*   coords   = (const int*)d_in[11];

    const int n = in_sizes[0] / 64;

    char* ws = (char*)d_ws;
    size_t o = 0;
    u64*   hash    = (u64*)(ws + o);   o += (size_t)HSIZE * 8;          // 4,194,304
    u32*   bm      = (u32*)(ws + o);   o += 2097152;                    // 2MB bitmap
    float* F_input = (float*)(ws + o); o += (size_t)n * 256;

    hipMemsetAsync(hash, 0xFF, (size_t)HSIZE * 8, stream);
    hipMemsetAsync(bm, 0, 2097152, stream);

    k_scatter<<<(n + 255)/256, 256, 0, stream>>>(coords, hash, bm, n);
    k_pre1<<<2048, 256, 0, stream>>>(feats, W_pre, ln_pre_w, ln_pre_b, F_input, n, 8192);
    k_segfinal<<<8192, 256, 0, stream>>>(F_input, feats, W_pos, alpha, conv_w,
                                         ln_w, ln_b, lnl_w, lnl_b,
                                         hash, bm, (float*)d_out);
}

// Round 15
// 273.454 us; speedup vs baseline: 1.4431x; 1.4431x over previous
//
#include <hip/hip_runtime.h>

// ELKUNet forward on MI355X — round 15. f32 device tensors (proven r1/r2/r4/r5).
// r14 lesson: self-conv on the segment-serial chain = +188us (conv instances
// 62K->262K, each a serial hash->feats->128FMA chain). Self-conv MUST be
// point-parallel. r13 lesson: one kernel can't hold 2 weight sets (VGPR 76).
// => recombine proven parts: k_pre1 + k_pre2 (r12, 16 named float4 each,
// resident) + k_segfinal (r13, selfconv input, self masked from conv loop).

typedef unsigned int u32;
typedef unsigned long long u64;

#define EPSV 1e-6f
#define HBITS 19
#define HSIZE (1u << HBITS)
#define HMASK (HSIZE - 1u)

template<int C,int R> __device__ __forceinline__ float dpp_add(float x){
    int y = __builtin_amdgcn_update_dpp(0, __float_as_int(x), C, R, 0xf, true);
    return x + __int_as_float(y);
}
// full 64-lane sum broadcast to all lanes; pure VALU + 1 readlane.
__device__ __forceinline__ float wave_sum(float x){
    x = dpp_add<0xB1,0xF>(x);   // xor 1
    x = dpp_add<0x4E,0xF>(x);   // xor 2
    x = dpp_add<0x141,0xF>(x);  // xor 4
    x = dpp_add<0x140,0xF>(x);  // xor 8
    x = dpp_add<0x142,0xA>(x);  // row_bcast:15
    x = dpp_add<0x143,0xC>(x);  // row_bcast:31
    return __int_as_float(__builtin_amdgcn_readlane(__float_as_int(x), 63));
}

__device__ __forceinline__ u32 hslot(u32 b){ return (b * 0x9E3779B1u) >> (32 - HBITS); }

__global__ void k_scatter(const int* __restrict__ coords, u64* __restrict__ hash,
                          u32* __restrict__ bm, int n){
    int i = blockIdx.x * blockDim.x + threadIdx.x;
    if(i < n){
        int4 c = ((const int4*)coords)[i];
        u32 b = ((u32)c.x << 16) | ((u32)c.y << 8) | (u32)c.z;
        atomicOr(&bm[b >> 5], 1u << (b & 31));
        u64 entry = ((u64)b << 32) | (u32)i;
        u32 s = hslot(b);
        while(atomicCAS(&hash[s], ~0ull, entry) != ~0ull) s = (s + 1) & HMASK;
    }
}

#define MV(f, wq) { a0 = fmaf((f).x, (wq).x, a0); a1 = fmaf((f).y, (wq).y, a1); \
                    a2 = fmaf((f).z, (wq).z, a2); a3 = fmaf((f).w, (wq).w, a3); }

// F_input = LN(feats @ W_pre^T). Weights in 16 NAMED float4 registers (r12).
__launch_bounds__(256, 2)
__global__ void k_pre1(const float* __restrict__ feats, const float* __restrict__ W_pre,
                       const float* __restrict__ lnw, const float* __restrict__ lnb,
                       float* __restrict__ F_input, int n, int nwaves){
    const int lane = threadIdx.x & 63;
    const int wave = (blockIdx.x * blockDim.x + threadIdx.x) >> 6;

    const float4* wr = (const float4*)(W_pre + (size_t)lane * 64);
    float4 w0 = wr[0],  w1 = wr[1],  w2 = wr[2],  w3 = wr[3];
    float4 w4 = wr[4],  w5 = wr[5],  w6 = wr[6],  w7 = wr[7];
    float4 w8 = wr[8],  w9 = wr[9],  wA = wr[10], wB = wr[11];
    float4 wC = wr[12], wD = wr[13], wE = wr[14], wF = wr[15];
    const float lw = lnw[lane], lb = lnb[lane];

    for(int i = wave; i < n; i += nwaves){
        const int si = __builtin_amdgcn_readfirstlane(i);
        const float4* fr = (const float4*)(feats + (size_t)si * 64);
        float a0=0.f, a1=0.f, a2=0.f, a3=0.f;
        MV(fr[0],  w0)  MV(fr[1],  w1)  MV(fr[2],  w2)  MV(fr[3],  w3)
        MV(fr[4],  w4)  MV(fr[5],  w5)  MV(fr[6],  w6)  MV(fr[7],  w7)
        MV(fr[8],  w8)  MV(fr[9],  w9)  MV(fr[10], wA)  MV(fr[11], wB)
        MV(fr[12], wC)  MV(fr[13], wD)  MV(fr[14], wE)  MV(fr[15], wF)
        float acc = (a0 + a1) + (a2 + a3);
        float m = wave_sum(acc) * (1.f/64.f);
        float t = acc - m;
        float v = wave_sum(t*t) * (1.f/64.f);
        F_input[(size_t)si*64 + lane] = t * rsqrtf(v + EPSV) * lw + lb;
    }
}

// selfconv = feats @ conv_w[13]. Weights in 16 NAMED float4 registers (r12).
__launch_bounds__(256, 2)
__global__ void k_pre2(const float* __restrict__ feats, const float* __restrict__ conv_w,
                       float* __restrict__ selfconv, int n, int nwaves){
    const int lane = threadIdx.x & 63;
    const int wave = (blockIdx.x * blockDim.x + threadIdx.x) >> 6;

    const float* cw = conv_w + 13*64*64 + lane;          // cw[j*64] = conv_w[13][j][lane]
#define LW(q) make_float4(cw[(4*(q))*64], cw[(4*(q)+1)*64], cw[(4*(q)+2)*64], cw[(4*(q)+3)*64])
    float4 w0 = LW(0),  w1 = LW(1),  w2 = LW(2),  w3 = LW(3);
    float4 w4 = LW(4),  w5 = LW(5),  w6 = LW(6),  w7 = LW(7);
    float4 w8 = LW(8),  w9 = LW(9),  wA = LW(10), wB = LW(11);
    float4 wC = LW(12), wD = LW(13), wE = LW(14), wF = LW(15);
#undef LW

    for(int i = wave; i < n; i += nwaves){
        const int si = __builtin_amdgcn_readfirstlane(i);
        const float4* fr = (const float4*)(feats + (size_t)si * 64);
        float a0=0.f, a1=0.f, a2=0.f, a3=0.f;
        MV(fr[0],  w0)  MV(fr[1],  w1)  MV(fr[2],  w2)  MV(fr[3],  w3)
        MV(fr[4],  w4)  MV(fr[5],  w5)  MV(fr[6],  w6)  MV(fr[7],  w7)
        MV(fr[8],  w8)  MV(fr[9],  w9)  MV(fr[10], wA)  MV(fr[11], wB)
        MV(fr[12], wC)  MV(fr[13], wD)  MV(fr[14], wE)  MV(fr[15], wF)
        selfconv[(size_t)si*64 + lane] = (a0 + a1) + (a2 + a3);
    }
}

// 1 wave = 1 segment. Pass1: enumerate own points (bitmap+hash), segment sums
// in registers. Pass2: per point: newF combine + 9-lane neighbor probe + rare
// conv (self masked; selfconv precomputed) + 2 LNs + relu + out. (r13 verbatim)
__launch_bounds__(256)
__global__ void k_segfinal(const float* __restrict__ F_input,
                           const float* __restrict__ selfconv,
                           const float* __restrict__ feats,
                           const float* __restrict__ W_pos, const float* __restrict__ alpha,
                           const float* __restrict__ conv_w,
                           const float* __restrict__ ln_w, const float* __restrict__ ln_b,
                           const float* __restrict__ lnl_w, const float* __restrict__ lnl_b,
                           const u64* __restrict__ hash, const u32* __restrict__ bm,
                           float* __restrict__ out){
    const u64* bm64 = (const u64*)bm;
    const int lane = threadIdx.x & 63;
    const int seg  = (blockIdx.x << 2) + (threadIdx.x >> 6);
    const int cx = seg >> 10, cy = (seg >> 5) & 31, cz = seg & 31;

    const int px = (cx << 3) + (lane >> 3), py = (cy << 3) + (lane & 7);
    u64 w = bm64[((size_t)px << 10) | ((u32)py << 2) | (u32)(cz >> 3)];
    u32 o8 = (u32)(w >> ((cz & 7) * 8)) & 0xffu;
    if(__ballot(o8 != 0u) == 0ull) return;

    const float wx = W_pos[lane*3+0], wy = W_pos[lane*3+1], wz = W_pos[lane*3+2];
    const float al = alpha[lane];

    // ---- pass 1: segment sums in registers ----
    float aC = 0.f, aS = 0.f, aL = 0.f;
    u32 t8 = o8;
    while(__ballot(t8 != 0u)){
        int myz = 0, pid = -1;
        if(t8){
            int dz = __ffs(t8) - 1; t8 &= t8 - 1;
            myz = (cz << 3) + dz;
            u32 b = ((u32)px << 16) | ((u32)py << 8) | (u32)myz;
            u32 s = hslot(b); u64 e;
            while((u32)((e = hash[s]) >> 32) != b) s = (s + 1) & HMASK;
            pid = (int)(u32)e;
        }
        u64 mm = __ballot(pid >= 0);
        while(mm){
            int l = __ffsll(mm) - 1; mm &= mm - 1;
            int p  = __builtin_amdgcn_readlane(pid, l);
            int pz = __builtin_amdgcn_readlane(myz, l);
            int qx = (cx << 3) + (l >> 3), qy = (cy << 3) + (l & 7);
            float F = F_input[(size_t)p * 64 + lane];
            float pos = ((float)qx*wx + (float)qy*wy + (float)pz*wz) * al;
            aC = fmaf(F, __cosf(pos), aC);
            aS = fmaf(F, __sinf(pos), aS);
            aL = fmaf(F, pos, aL);
        }
    }
    const float inv = 1.f / wave_sum((float)__popc(o8));
    const float vCv = aC * inv, vSv = aS * inv, vLv = aL * inv;
    const float lnwv = ln_w[lane], lnbv = ln_b[lane];
    const float llwv = lnl_w[lane], llbv = lnl_b[lane];

    // ---- pass 2: per point finale (hash/F re-probes are L1-hot) ----
    t8 = o8;
    while(__ballot(t8 != 0u)){
        int myz = 0, pid = -1;
        if(t8){
            int dz = __ffs(t8) - 1; t8 &= t8 - 1;
            myz = (cz << 3) + dz;
            u32 b = ((u32)px << 16) | ((u32)py << 8) | (u32)myz;
            u32 s = hslot(b); u64 e;
            while((u32)((e = hash[s]) >> 32) != b) s = (s + 1) & HMASK;
            pid = (int)(u32)e;
        }
        u64 mm = __ballot(pid >= 0);
        while(mm){
            int l = __ffsll(mm) - 1; mm &= mm - 1;
            int p  = __builtin_amdgcn_readlane(pid, l);
            int pz = __builtin_amdgcn_readlane(myz, l);
            int qx = (cx << 3) + (l >> 3), qy = (cy << 3) + (l & 7);

            float F  = F_input[(size_t)p * 64 + lane];     // L1-hot
            float Sc = selfconv[(size_t)p * 64 + lane];

            // neighbor probe: lanes 0..8 cover (dx,dy); 3 z-bits each
            u32 m3 = 0;
            if(lane < 9){
                int nx = qx + lane/3 - 1, ny = qy + lane%3 - 1;
                if(((u32)nx < 256u) && ((u32)ny < 256u)){
                    const u64* wp = bm64 + (((size_t)nx << 10) | ((u32)ny << 2));
                    int zb = pz & 63;
                    if(zb >= 1 && zb <= 62){
                        u64 ww = wp[pz >> 6];
                        m3 = (u32)((ww >> (zb - 1)) & 7ull);
                    } else {
#pragma unroll
                        for(int t = 0; t < 3; ++t){
                            int zz = pz + t - 1;
                            if((u32)zz < 256u){
                                u64 ww = wp[zz >> 6];
                                m3 |= (u32)((ww >> (zz & 63)) & 1ull) << t;
                            }
                        }
                    }
                }
            }
            u64 b0 = __ballot(m3 & 1u);
            u64 b1 = __ballot(m3 & 2u) & ~(1ull << 4);   // drop self (l2=4, dz=0)
            u64 b2 = __ballot(m3 & 4u);

            float pos = ((float)qx*wx + (float)qy*wy + (float)pz*wz) * al;
            float sn = __sinf(pos), cs = __cosf(pos);
            float newF = fmaf(vCv, cs, fmaf(vSv, sn, vLv - F*pos));
            float local = Sc;

#pragma unroll
            for(int t = 0; t < 3; ++t){
                u64 mm2 = (t == 0) ? b0 : ((t == 1) ? b1 : b2);
                while(mm2){
                    int l2 = __ffsll(mm2) - 1; mm2 &= mm2 - 1;
                    int nx = qx + l2/3 - 1, ny = qy + l2%3 - 1, nz = pz + t - 1;
                    int k = 3*l2 + t;
                    u32 nb = ((u32)nx << 16) | ((u32)ny << 8) | (u32)nz;
                    u32 s = hslot(nb); u64 e;
                    while((u32)((e = hash[s]) >> 32) != nb) s = (s + 1) & HMASK;
                    const int pin = (int)(u32)e;
                    const float4* gv = (const float4*)(feats + (size_t)pin * 64);
                    const float* cw = conv_w + (size_t)k * 4096;
#pragma unroll 4
                    for(int q = 0; q < 16; ++q){
                        float4 g = gv[q];
                        local = fmaf(g.x, cw[(4*q    )*64 + lane], local);
                        local = fmaf(g.y, cw[(4*q + 1)*64 + lane], local);
                        local = fmaf(g.z, cw[(4*q + 2)*64 + lane], local);
                        local = fmaf(g.w, cw[(4*q + 3)*64 + lane], local);
                    }
                }
            }

            float m1 = wave_sum(newF) * (1.f/64.f);
            float t1 = newF - m1;
            float v1 = wave_sum(t1*t1) * (1.f/64.f);
            float a1 = t1 * rsqrtf(v1 + EPSV) * lnwv + lnbv;

            float m2 = wave_sum(local) * (1.f/64.f);
            float t2 = local - m2;
            float v2 = wave_sum(t2*t2) * (1.f/64.f);
            float a2 = t2 * rsqrtf(v2 + EPSV) * llwv + llbv;

            out[(size_t)p*64 + lane] = fmaxf(a1 + a2, 0.f);
        }
    }
}

extern "C" void kernel_launch(void* const* d_in, const int* in_sizes, int n_in,
                              void* d_out, int out_size, void* d_ws, size_t ws_size,
                              hipStream_t stream) {
    (void)n_in; (void)out_size; (void)ws_size;
    const float* feats    = (const float*)d_in[0];
    const float* W_pre    = (const float*)d_in[1];
    const float* ln_pre_w = (const float*)d_in[2];
    const float* ln_pre_b = (const float*)d_in[3];
    const float* W_pos    = (const float*)d_in[4];
    const float* alpha    = (const float*)d_in[5];
    const float* conv_w   = (const float*)d_in[6];
    const float* ln_w     = (const float*)d_in[7];
    const float* ln_b     = (const float*)d_in[8];
    const float* lnl_w    = (const float*)d_in[9];
    const float* lnl_b    = (const float*)d_in[10];
    const int*   coords   = (const int*)d_in[11];

    const int n = in_sizes[0] / 64;

    char* ws = (char*)d_ws;
    size_t o = 0;
    u64*   hash    = (u64*)(ws + o);   o += (size_t)HSIZE * 8;          // 4,194,304
    u32*   bm      = (u32*)(ws + o);   o += 2097152;                    // 2MB bitmap
    float* F_input = (float*)(ws + o); o += (size_t)n * 256;
    float* selfconv= (float*)(ws + o); o += (size_t)n * 256;

    hipMemsetAsync(hash, 0xFF, (size_t)HSIZE * 8, stream);
    hipMemsetAsync(bm, 0, 2097152, stream);

    k_scatter<<<(n + 255)/256, 256, 0, stream>>>(coords, hash, bm, n);
    k_pre1<<<2048, 256, 0, stream>>>(feats, W_pre, ln_pre_w, ln_pre_b, F_input, n, 8192);
    k_pre2<<<2048, 256, 0, stream>>>(feats, conv_w, selfconv, n, 8192);
    k_segfinal<<<8192, 256, 0, stream>>>(F_input, selfconv, feats, W_pos, alpha,
                                         conv_w, ln_w, ln_b, lnl_w, lnl_b,
                                         hash, bm, (float*)d_out);
}

// Round 16
// 269.633 us; speedup vs baseline: 1.4636x; 1.0142x over previous
//
#include <hip/hip_runtime.h>

// ELKUNet forward on MI355X — round 16. f32 device tensors (proven r1/r2/r4/r5).
// r15 accounting: pre1+pre2 = ~130us = r13's fused preB -> pre cost is NOT
// weight residency; it's the per-point wave-uniform scalar row-load chain
// (16 s_loads ~500cyc each pt, 4 waves/SIMD). Fix: LDS-tile structure —
// stage 64-point tile with coalesced vector loads, compute via wave-uniform
// ds_read_b128 (broadcast, conflict-free). Weights in 16 named float4 (r12).
// Two single-role kernels (residency saga: no branchy merges).
// k_scatter + k_segfinal (r13) unchanged.

typedef unsigned int u32;
typedef unsigned long long u64;

#define EPSV 1e-6f
#define HBITS 19
#define HSIZE (1u << HBITS)
#define HMASK (HSIZE - 1u)

template<int C,int R> __device__ __forceinline__ float dpp_add(float x){
    int y = __builtin_amdgcn_update_dpp(0, __float_as_int(x), C, R, 0xf, true);
    return x + __int_as_float(y);
}
// full 64-lane sum broadcast to all lanes; pure VALU + 1 readlane.
__device__ __forceinline__ float wave_sum(float x){
    x = dpp_add<0xB1,0xF>(x);   // xor 1
    x = dpp_add<0x4E,0xF>(x);   // xor 2
    x = dpp_add<0x141,0xF>(x);  // xor 4
    x = dpp_add<0x140,0xF>(x);  // xor 8
    x = dpp_add<0x142,0xA>(x);  // row_bcast:15
    x = dpp_add<0x143,0xC>(x);  // row_bcast:31
    return __int_as_float(__builtin_amdgcn_readlane(__float_as_int(x), 63));
}

__device__ __forceinline__ u32 hslot(u32 b){ return (b * 0x9E3779B1u) >> (32 - HBITS); }

__global__ void k_scatter(const int* __restrict__ coords, u64* __restrict__ hash,
                          u32* __restrict__ bm, int n){
    int i = blockIdx.x * blockDim.x + threadIdx.x;
    if(i < n){
        int4 c = ((const int4*)coords)[i];
        u32 b = ((u32)c.x << 16) | ((u32)c.y << 8) | (u32)c.z;
        atomicOr(&bm[b >> 5], 1u << (b & 31));
        u64 entry = ((u64)b << 32) | (u32)i;
        u32 s = hslot(b);
        while(atomicCAS(&hash[s], ~0ull, entry) != ~0ull) s = (s + 1) & HMASK;
    }
}

#define MV(f, wq) { a0 = fmaf((f).x, (wq).x, a0); a1 = fmaf((f).y, (wq).y, a1); \
                    a2 = fmaf((f).z, (wq).z, a2); a3 = fmaf((f).w, (wq).w, a3); }

// F_input = LN(feats @ W_pre^T). Tile-staged activations; resident weights.
__launch_bounds__(256, 2)
__global__ void k_pre1(const float* __restrict__ feats, const float* __restrict__ W_pre,
                       const float* __restrict__ lnw, const float* __restrict__ lnb,
                       float* __restrict__ F_input, int n){
    __shared__ float tile[4096];                 // 64 points x 64 ch = 16KB
    const int lane = threadIdx.x & 63;
    const int wid  = threadIdx.x >> 6;
    const int tbase = blockIdx.x << 6;

    const float4* wr = (const float4*)(W_pre + (size_t)lane * 64);
    float4 w0 = wr[0],  w1 = wr[1],  w2 = wr[2],  w3 = wr[3];
    float4 w4 = wr[4],  w5 = wr[5],  w6 = wr[6],  w7 = wr[7];
    float4 w8 = wr[8],  w9 = wr[9],  wA = wr[10], wB = wr[11];
    float4 wC = wr[12], wD = wr[13], wE = wr[14], wF = wr[15];
    const float lw = lnw[lane], lb = lnb[lane];

    // stage tile: coalesced float4 loads, linear LDS writes
#pragma unroll
    for(int r = 0; r < 4; ++r){
        int idx = (r << 8) + threadIdx.x;        // float4 slot 0..1023
        int pt  = tbase + (idx >> 4);
        float4 v = make_float4(0.f, 0.f, 0.f, 0.f);
        if(pt < n) v = ((const float4*)feats)[(size_t)pt * 16 + (idx & 15)];
        ((float4*)tile)[idx] = v;
    }
    __syncthreads();

    const int p0 = wid << 4;                     // 16 points per wave
#pragma unroll 1
    for(int p = 0; p < 16; ++p){
        const int pt = tbase + p0 + p;
        if(pt >= n) break;
        const float4* fr = (const float4*)(tile + ((p0 + p) << 6));  // uniform -> broadcast
        float a0=0.f, a1=0.f, a2=0.f, a3=0.f;
        MV(fr[0],  w0)  MV(fr[1],  w1)  MV(fr[2],  w2)  MV(fr[3],  w3)
        MV(fr[4],  w4)  MV(fr[5],  w5)  MV(fr[6],  w6)  MV(fr[7],  w7)
        MV(fr[8],  w8)  MV(fr[9],  w9)  MV(fr[10], wA)  MV(fr[11], wB)
        MV(fr[12], wC)  MV(fr[13], wD)  MV(fr[14], wE)  MV(fr[15], wF)
        float acc = (a0 + a1) + (a2 + a3);
        float m = wave_sum(acc) * (1.f/64.f);
        float t = acc - m;
        float v = wave_sum(t*t) * (1.f/64.f);
        F_input[(size_t)pt*64 + lane] = t * rsqrtf(v + EPSV) * lw + lb;
    }
}

// selfconv = feats @ conv_w[13]. Same tile structure.
__launch_bounds__(256, 2)
__global__ void k_pre2(const float* __restrict__ feats, const float* __restrict__ conv_w,
                       float* __restrict__ selfconv, int n){
    __shared__ float tile[4096];
    const int lane = threadIdx.x & 63;
    const int wid  = threadIdx.x >> 6;
    const int tbase = blockIdx.x << 6;

    const float* cw = conv_w + 13*64*64 + lane;  // cw[j*64] = conv_w[13][j][lane]
#define LW(q) make_float4(cw[(4*(q))*64], cw[(4*(q)+1)*64], cw[(4*(q)+2)*64], cw[(4*(q)+3)*64])
    float4 w0 = LW(0),  w1 = LW(1),  w2 = LW(2),  w3 = LW(3);
    float4 w4 = LW(4),  w5 = LW(5),  w6 = LW(6),  w7 = LW(7);
    float4 w8 = LW(8),  w9 = LW(9),  wA = LW(10), wB = LW(11);
    float4 wC = LW(12), wD = LW(13), wE = LW(14), wF = LW(15);
#undef LW

#pragma unroll
    for(int r = 0; r < 4; ++r){
        int idx = (r << 8) + threadIdx.x;
        int pt  = tbase + (idx >> 4);
        float4 v = make_float4(0.f, 0.f, 0.f, 0.f);
        if(pt < n) v = ((const float4*)feats)[(size_t)pt * 16 + (idx & 15)];
        ((float4*)tile)[idx] = v;
    }
    __syncthreads();

    const int p0 = wid << 4;
#pragma unroll 1
    for(int p = 0; p < 16; ++p){
        const int pt = tbase + p0 + p;
        if(pt >= n) break;
        const float4* fr = (const float4*)(tile + ((p0 + p) << 6));
        float a0=0.f, a1=0.f, a2=0.f, a3=0.f;
        MV(fr[0],  w0)  MV(fr[1],  w1)  MV(fr[2],  w2)  MV(fr[3],  w3)
        MV(fr[4],  w4)  MV(fr[5],  w5)  MV(fr[6],  w6)  MV(fr[7],  w7)
        MV(fr[8],  w8)  MV(fr[9],  w9)  MV(fr[10], wA)  MV(fr[11], wB)
        MV(fr[12], wC)  MV(fr[13], wD)  MV(fr[14], wE)  MV(fr[15], wF)
        selfconv[(size_t)pt*64 + lane] = (a0 + a1) + (a2 + a3);
    }
}

// 1 wave = 1 segment. Pass1: enumerate own points (bitmap+hash), segment sums
// in registers. Pass2: per point: newF combine + 9-lane neighbor probe + rare
// conv (self masked; selfconv precomputed) + 2 LNs + relu + out. (r13 verbatim)
__launch_bounds__(256)
__global__ void k_segfinal(const float* __restrict__ F_input,
                           const float* __restrict__ selfconv,
                           const float* __restrict__ feats,
                           const float* __restrict__ W_pos, const float* __restrict__ alpha,
                           const float* __restrict__ conv_w,
                           const float* __restrict__ ln_w, const float* __restrict__ ln_b,
                           const float* __restrict__ lnl_w, const float* __restrict__ lnl_b,
                           const u64* __restrict__ hash, const u32* __restrict__ bm,
                           float* __restrict__ out){
    const u64* bm64 = (const u64*)bm;
    const int lane = threadIdx.x & 63;
    const int seg  = (blockIdx.x << 2) + (threadIdx.x >> 6);
    const int cx = seg >> 10, cy = (seg >> 5) & 31, cz = seg & 31;

    const int px = (cx << 3) + (lane >> 3), py = (cy << 3) + (lane & 7);
    u64 w = bm64[((size_t)px << 10) | ((u32)py << 2) | (u32)(cz >> 3)];
    u32 o8 = (u32)(w >> ((cz & 7) * 8)) & 0xffu;
    if(__ballot(o8 != 0u) == 0ull) return;

    const float wx = W_pos[lane*3+0], wy = W_pos[lane*3+1], wz = W_pos[lane*3+2];
    const float al = alpha[lane];

    // ---- pass 1: segment sums in registers ----
    float aC = 0.f, aS = 0.f, aL = 0.f;
    u32 t8 = o8;
    while(__ballot(t8 != 0u)){
        int myz = 0, pid = -1;
        if(t8){
            int dz = __ffs(t8) - 1; t8 &= t8 - 1;
            myz = (cz << 3) + dz;
            u32 b = ((u32)px << 16) | ((u32)py << 8) | (u32)myz;
            u32 s = hslot(b); u64 e;
            while((u32)((e = hash[s]) >> 32) != b) s = (s + 1) & HMASK;
            pid = (int)(u32)e;
        }
        u64 mm = __ballot(pid >= 0);
        while(mm){
            int l = __ffsll(mm) - 1; mm &= mm - 1;
            int p  = __builtin_amdgcn_readlane(pid, l);
            int pz = __builtin_amdgcn_readlane(myz, l);
            int qx = (cx << 3) + (l >> 3), qy = (cy << 3) + (l & 7);
            float F = F_input[(size_t)p * 64 + lane];
            float pos = ((float)qx*wx + (float)qy*wy + (float)pz*wz) * al;
            aC = fmaf(F, __cosf(pos), aC);
            aS = fmaf(F, __sinf(pos), aS);
            aL = fmaf(F, pos, aL);
        }
    }
    const float inv = 1.f / wave_sum((float)__popc(o8));
    const float vCv = aC * inv, vSv = aS * inv, vLv = aL * inv;
    const float lnwv = ln_w[lane], lnbv = ln_b[lane];
    const float llwv = lnl_w[lane], llbv = lnl_b[lane];

    // ---- pass 2: per point finale (hash/F re-probes are L1-hot) ----
    t8 = o8;
    while(__ballot(t8 != 0u)){
        int myz = 0, pid = -1;
        if(t8){
            int dz = __ffs(t8) - 1; t8 &= t8 - 1;
            myz = (cz << 3) + dz;
            u32 b = ((u32)px << 16) | ((u32)py << 8) | (u32)myz;
            u32 s = hslot(b); u64 e;
            while((u32)((e = hash[s]) >> 32) != b) s = (s + 1) & HMASK;
            pid = (int)(u32)e;
        }
        u64 mm = __ballot(pid >= 0);
        while(mm){
            int l = __ffsll(mm) - 1; mm &= mm - 1;
            int p  = __builtin_amdgcn_readlane(pid, l);
            int pz = __builtin_amdgcn_readlane(myz, l);
            int qx = (cx << 3) + (l >> 3), qy = (cy << 3) + (l & 7);

            float F  = F_input[(size_t)p * 64 + lane];     // L1-hot
            float Sc = selfconv[(size_t)p * 64 + lane];

            // neighbor probe: lanes 0..8 cover (dx,dy); 3 z-bits each
            u32 m3 = 0;
            if(lane < 9){
                int nx = qx + lane/3 - 1, ny = qy + lane%3 - 1;
                if(((u32)nx < 256u) && ((u32)ny < 256u)){
                    const u64* wp = bm64 + (((size_t)nx << 10) | ((u32)ny << 2));
                    int zb = pz & 63;
                    if(zb >= 1 && zb <= 62){
                        u64 ww = wp[pz >> 6];
                        m3 = (u32)((ww >> (zb - 1)) & 7ull);
                    } else {
#pragma unroll
                        for(int t = 0; t < 3; ++t){
                            int zz = pz + t - 1;
                            if((u32)zz < 256u){
                                u64 ww = wp[zz >> 6];
                                m3 |= (u32)((ww >> (zz & 63)) & 1ull) << t;
                            }
                        }
                    }
                }
            }
            u64 b0 = __ballot(m3 & 1u);
            u64 b1 = __ballot(m3 & 2u) & ~(1ull << 4);   // drop self (l2=4, dz=0)
            u64 b2 = __ballot(m3 & 4u);

            float pos = ((float)qx*wx + (float)qy*wy + (float)pz*wz) * al;
            float sn = __sinf(pos), cs = __cosf(pos);
            float newF = fmaf(vCv, cs, fmaf(vSv, sn, vLv - F*pos));
            float local = Sc;

#pragma unroll
            for(int t = 0; t < 3; ++t){
                u64 mm2 = (t == 0) ? b0 : ((t == 1) ? b1 : b2);
                while(mm2){
                    int l2 = __ffsll(mm2) - 1; mm2 &= mm2 - 1;
                    int nx = qx + l2/3 - 1, ny = qy + l2%3 - 1, nz = pz + t - 1;
                    int k = 3*l2 + t;
                    u32 nb = ((u32)nx << 16) | ((u32)ny << 8) | (u32)nz;
                    u32 s = hslot(nb); u64 e;
                    while((u32)((e = hash[s]) >> 32) != nb) s = (s + 1) & HMASK;
                    const int pin = (int)(u32)e;
                    const float4* gv = (const float4*)(feats + (size_t)pin * 64);
                    const float* cw = conv_w + (size_t)k * 4096;
#pragma unroll 4
                    for(int q = 0; q < 16; ++q){
                        float4 g = gv[q];
                        local = fmaf(g.x, cw[(4*q    )*64 + lane], local);
                        local = fmaf(g.y, cw[(4*q + 1)*64 + lane], local);
                        local = fmaf(g.z, cw[(4*q + 2)*64 + lane], local);
                        local = fmaf(g.w, cw[(4*q + 3)*64 + lane], local);
                    }
                }
            }

            float m1 = wave_sum(newF) * (1.f/64.f);
            float t1 = newF - m1;
            float v1 = wave_sum(t1*t1) * (1.f/64.f);
            float a1 = t1 * rsqrtf(v1 + EPSV) * lnwv + lnbv;

            float m2 = wave_sum(local) * (1.f/64.f);
            float t2 = local - m2;
            float v2 = wave_sum(t2*t2) * (1.f/64.f);
            float a2 = t2 * rsqrtf(v2 + EPSV) * llwv + llbv;

            out[(size_t)p*64 + lane] = fmaxf(a1 + a2, 0.f);
        }
    }
}

extern "C" void kernel_launch(void* const* d_in, const int* in_sizes, int n_in,
                              void* d_out, int out_size, void* d_ws, size_t ws_size,
                              hipStream_t stream) {
    (void)n_in; (void)out_size; (void)ws_size;
    const float* feats    = (const float*)d_in[0];
    const float* W_pre    = (const float*)d_in[1];
    const float* ln_pre_w = (const float*)d_in[2];
    const float* ln_pre_b = (const float*)d_in[3];
    const float* W_pos    = (const float*)d_in[4];
    const float* alpha    = (const float*)d_in[5];
    const float* conv_w   = (const float*)d_in[6];
    const float* ln_w     = (const float*)d_in[7];
    const float* ln_b     = (const float*)d_in[8];
    const float* lnl_w    = (const float*)d_in[9];
    const float* lnl_b    = (const float*)d_in[10];
    const int*   coords   = (const int*)d_in[11];

    const int n = in_sizes[0] / 64;

    char* ws = (char*)d_ws;
    size_t o = 0;
    u64*   hash    = (u64*)(ws + o);   o += (size_t)HSIZE * 8;          // 4,194,304
    u32*   bm      = (u32*)(ws + o);   o += 2097152;                    // 2MB bitmap
    float* F_input = (float*)(ws + o); o += (size_t)n * 256;
    float* selfconv= (float*)(ws + o); o += (size_t)n * 256;

    hipMemsetAsync(hash, 0xFF, (size_t)HSIZE * 8, stream);
    hipMemsetAsync(bm, 0, 2097152, stream);

    const int tiles = (n + 63) / 64;             // 3125
    k_scatter<<<(n + 255)/256, 256, 0, stream>>>(coords, hash, bm, n);
    k_pre1<<<tiles, 256, 0, stream>>>(feats, W_pre, ln_pre_w, ln_pre_b, F_input, n);
    k_pre2<<<tiles, 256, 0, stream>>>(feats, conv_w, selfconv, n);
    k_segfinal<<<8192, 256, 0, stream>>>(F_input, selfconv, feats, W_pos, alpha,
                                         conv_w, ln_w, ln_b, lnl_w, lnl_b,
                                         hash, bm, (float*)d_out);
}